// Round 8
// baseline (743.071 us; speedup 1.0000x reference)
//
#include <hip/hip_runtime.h>

#define DIM 128
#define NROWS 2048
#define NDP 64  // d-pairs

typedef float v2f __attribute__((ext_vector_type(2)));
typedef _Float16 h2 __attribute__((ext_vector_type(2)));

static __device__ __forceinline__ h2 u2h(unsigned u) {
  return __builtin_bit_cast(h2, u);
}
static __device__ __forceinline__ unsigned h2u(h2 h) {
  return __builtin_bit_cast(unsigned, h);
}
// guaranteed v_pk_max_f16 (ROCm header lacks __hmax2; builtin may scalarize)
static __device__ __forceinline__ h2 pk_max(h2 a, h2 b) {
  h2 r;
  asm("v_pk_max_f16 %0, %1, %2" : "=v"(r) : "v"(a), "v"(b));
  return r;
}

// ---------------------------------------------------------------------------
// prep v7: hi2T[dp][n] = half2(hi[2dp][n], hi[2dp+1][n]); hj2T likewise + b1.
// grid (512 row-tiles of 4, 2 sides) = 1024 blocks (4/CU, 16 waves/CU).
// Thread = 1 d-pair x 1 row. z row read from LDS as float4 (32 b128/thread);
// W1 column-pair from global, 8 B/lane coalesced, L1-resident (4x wave reuse).
// ---------------------------------------------------------------------------
__global__ __launch_bounds__(256) void prep_kernel(
    const float* __restrict__ z_i, const float* __restrict__ z_j,
    const float* __restrict__ W1, const float* __restrict__ b1,
    unsigned* __restrict__ hi2T, unsigned* __restrict__ hj2T) {
  __shared__ float zs[4 * DIM];  // 2 KB

  const int t = threadIdx.x;
  const int side = blockIdx.y;
  const int rowbase = blockIdx.x * 4;

  const float* z = (side ? z_j : z_i) + (size_t)rowbase * DIM;
  if (t < 128) ((float4*)zs)[t] = ((const float4*)z)[t];
  __syncthreads();

  const int dp = t & 63;   // d-pair (lane-consecutive -> coalesced W loads)
  const int row = t >> 6;  // 0..3
  const float* wcol = W1 + side * (DIM * DIM) + dp * 2;
  const float* zr = zs + row * DIM;

  v2f acc = {0.f, 0.f};
#pragma unroll 2
  for (int k0 = 0; k0 < DIM; k0 += 4) {
    const float4 z4 = *(const float4*)(zr + k0);  // ds_read_b128, broadcast
    const float zv[4] = {z4.x, z4.y, z4.z, z4.w};
#pragma unroll
    for (int q = 0; q < 4; ++q) {
      const v2f wv = *(const v2f*)(wcol + (size_t)(k0 + q) * DIM);  // L1 hit
      acc = __builtin_elementwise_fma(wv, (v2f){zv[q], zv[q]}, acc);
    }
  }

  if (side) acc += *(const v2f*)(b1 + dp * 2);
  unsigned* dst = (side ? hj2T : hi2T) + (size_t)dp * NROWS + rowbase + row;
  *dst = h2u((h2){(_Float16)acc.x, (_Float16)acc.y});
}

// ---------------------------------------------------------------------------
// score v7: out[i][j] = b2 + sum_dp dot2(relu(hi2[dp][i]+hj2[dp][j]), w2[dp])
// Tile 64x64, grid (32,32) = 1024 blocks (4/CU, 16 waves/CU), 32.25 KB LDS,
// micro 4i x 4j. dp loop FULLY UNROLLED (immediate LDS offsets) with explicit
// one-iteration prefetch of both uint4 tile reads. Packed core:
// v_pk_add_f16 + v_pk_max_f16 (inline asm) + v_dot2_f32_f16.
// ---------------------------------------------------------------------------
__global__ __launch_bounds__(256, 4) void score_kernel(
    const unsigned* __restrict__ hi2T, const unsigned* __restrict__ hj2T,
    const float* __restrict__ W2, const float* __restrict__ b2p,
    float* __restrict__ out) {
  __shared__ unsigned his2[NDP * 64];  // 16 KB  [dp][i]
  __shared__ unsigned hjs2[NDP * 64];  // 16 KB  [dp][j]
  __shared__ unsigned w2s[NDP];        // 256 B

  const int t = threadIdx.x;
  const int ibase = blockIdx.y * 64;
  const int jbase = blockIdx.x * 64;
  const float bias = *b2p;

#pragma unroll
  for (int rep = 0; rep < 4; ++rep) {
    const int idx = rep * 256 + t;
    const int dp = idx >> 4, c = (idx & 15) * 4;
    *(uint4*)(his2 + dp * 64 + c) =
        *(const uint4*)(hi2T + (size_t)dp * NROWS + ibase + c);
    *(uint4*)(hjs2 + dp * 64 + c) =
        *(const uint4*)(hj2T + (size_t)dp * NROWS + jbase + c);
  }
  if (t < NDP) {
    const v2f wp = *(const v2f*)(W2 + t * 2);
    w2s[t] = h2u((h2){(_Float16)wp.x, (_Float16)wp.y});
  }
  __syncthreads();  // the only barrier

  const int tx = t & 15;
  const int ty = t >> 4;
  const unsigned* hb = his2 + ty * 4;  // stride-64 walk, 2-way = free
  const unsigned* jb = hjs2 + tx * 4;

  float facc[4][4];
#pragma unroll
  for (int ii = 0; ii < 4; ++ii)
#pragma unroll
    for (int jj = 0; jj < 4; ++jj) facc[ii][jj] = 0.f;

  const h2 zero = u2h(0u);
  uint4 hu = *(const uint4*)(hb);
  uint4 ju = *(const uint4*)(jb);

#pragma unroll
  for (int dp = 0; dp < NDP; ++dp) {
    uint4 hn, jn;
    if (dp < NDP - 1) {  // prefetch next dp (immediate LDS offsets)
      hn = *(const uint4*)(hb + (dp + 1) * 64);
      jn = *(const uint4*)(jb + (dp + 1) * 64);
    }
    const h2 wp = u2h(w2s[dp]);  // LDS broadcast b32
    const h2 hiv[4] = {u2h(hu.x), u2h(hu.y), u2h(hu.z), u2h(hu.w)};
    const h2 hjv[4] = {u2h(ju.x), u2h(ju.y), u2h(ju.z), u2h(ju.w)};
#pragma unroll
    for (int ii = 0; ii < 4; ++ii) {
#pragma unroll
      for (int jj = 0; jj < 4; ++jj) {
        const h2 s = pk_max(hiv[ii] + hjv[jj], zero);
        facc[ii][jj] = __builtin_amdgcn_fdot2(s, wp, facc[ii][jj], false);
      }
    }
    hu = hn;
    ju = jn;
  }

#pragma unroll
  for (int ii = 0; ii < 4; ++ii) {
    float* o = out + (size_t)(ibase + ty * 4 + ii) * NROWS + jbase + tx * 4;
    *(float4*)o = (float4){facc[ii][0] + bias, facc[ii][1] + bias,
                           facc[ii][2] + bias, facc[ii][3] + bias};
  }
}

extern "C" void kernel_launch(void* const* d_in, const int* in_sizes, int n_in,
                              void* d_out, int out_size, void* d_ws, size_t ws_size,
                              hipStream_t stream) {
  const float* z_i = (const float*)d_in[0];
  const float* z_j = (const float*)d_in[1];
  const float* W1  = (const float*)d_in[2];
  const float* b1  = (const float*)d_in[3];
  const float* W2  = (const float*)d_in[4];
  const float* b2  = (const float*)d_in[5];
  float* out = (float*)d_out;

  unsigned* hi2T = (unsigned*)d_ws;             // [64][2048] half2 -> 512 KB
  unsigned* hj2T = hi2T + (size_t)NDP * NROWS;  // [64][2048] half2 -> 512 KB

  prep_kernel<<<dim3(512, 2), 256, 0, stream>>>(z_i, z_j, W1, b1, hi2T, hj2T);
  score_kernel<<<dim3(32, 32), 256, 0, stream>>>(hi2T, hj2T, W2, b2, out);
}

// Round 9
// 113.821 us; speedup vs baseline: 6.5284x; 6.5284x over previous
//
#include <hip/hip_runtime.h>

#define DIM 128
#define NROWS 2048
#define NDP 64  // d-pairs

typedef float v2f __attribute__((ext_vector_type(2)));
typedef _Float16 h2 __attribute__((ext_vector_type(2)));

static __device__ __forceinline__ h2 u2h(unsigned u) { return __builtin_bit_cast(h2, u); }
static __device__ __forceinline__ unsigned h2u(h2 h) { return __builtin_bit_cast(unsigned, h); }

// ---------------------------------------------------------------------------
// prep v7 (validated in R8): hi2T[dp][n] = half2(hi[2dp][n], hi[2dp+1][n]);
// hj2T likewise + b1. grid (512 row-tiles of 4, 2 sides) = 1024 blocks
// (4/CU, 16 waves/CU). Thread = 1 d-pair x 1 row. z row via float4 LDS reads
// (32 ds_read_b128/thread); W1 column-pair coalesced 8 B/lane, L1/L2-resident.
// ---------------------------------------------------------------------------
__global__ __launch_bounds__(256) void prep_kernel(
    const float* __restrict__ z_i, const float* __restrict__ z_j,
    const float* __restrict__ W1, const float* __restrict__ b1,
    unsigned* __restrict__ hi2T, unsigned* __restrict__ hj2T) {
  __shared__ float zs[4 * DIM];  // 2 KB

  const int t = threadIdx.x;
  const int side = blockIdx.y;
  const int rowbase = blockIdx.x * 4;

  const float* z = (side ? z_j : z_i) + (size_t)rowbase * DIM;
  if (t < 128) ((float4*)zs)[t] = ((const float4*)z)[t];
  __syncthreads();

  const int dp = t & 63;   // d-pair (lane-consecutive -> coalesced W loads)
  const int row = t >> 6;  // 0..3
  const float* wcol = W1 + side * (DIM * DIM) + dp * 2;
  const float* zr = zs + row * DIM;

  v2f acc = {0.f, 0.f};
#pragma unroll 2
  for (int k0 = 0; k0 < DIM; k0 += 4) {
    const float4 z4 = *(const float4*)(zr + k0);  // ds_read_b128, broadcast
    const float zv[4] = {z4.x, z4.y, z4.z, z4.w};
#pragma unroll
    for (int q = 0; q < 4; ++q) {
      const v2f wv = *(const v2f*)(wcol + (size_t)(k0 + q) * DIM);  // L1 hit
      acc = __builtin_elementwise_fma(wv, (v2f){zv[q], zv[q]}, acc);
    }
  }

  if (side) acc += *(const v2f*)(b1 + dp * 2);
  unsigned* dst = (side ? hj2T : hi2T) + (size_t)dp * NROWS + rowbase + row;
  *dst = h2u((h2){(_Float16)acc.x, (_Float16)acc.y});
}

// ---------------------------------------------------------------------------
// score (exact R4, proven VGPR=32 / no spills):
// out[i][j] = b2 + sum_dp dot2(relu(hi2[dp][i]+hj2[dp][j]), w2[dp])
// grid (32,32) = 1024 blocks (4/CU), 64x64 tile, micro 4i x 4j, 32.25 KB LDS,
// all LDS reads 16B lane-stride (2-way = free). Core: v_pk_add_f16 +
// elementwise_max + v_dot2_f32_f16.
// ---------------------------------------------------------------------------
__global__ __launch_bounds__(256, 4) void score_kernel(
    const unsigned* __restrict__ hi2T, const unsigned* __restrict__ hj2T,
    const float* __restrict__ W2, const float* __restrict__ b2p,
    float* __restrict__ out) {
  __shared__ unsigned his2[NDP * 64];  // 16 KB  [dp][i]
  __shared__ unsigned hjs2[NDP * 64];  // 16 KB  [dp][j]
  __shared__ unsigned w2s[NDP];        // 256 B

  const int t = threadIdx.x;
  const int ibase = blockIdx.y * 64;
  const int jbase = blockIdx.x * 64;
  const float bias = *b2p;

#pragma unroll
  for (int rep = 0; rep < 4; ++rep) {
    const int idx = rep * 256 + t;
    const int dp = idx >> 4, c = (idx & 15) * 4;
    *(uint4*)(his2 + dp * 64 + c) =
        *(const uint4*)(hi2T + (size_t)dp * NROWS + ibase + c);
    *(uint4*)(hjs2 + dp * 64 + c) =
        *(const uint4*)(hj2T + (size_t)dp * NROWS + jbase + c);
  }
  if (t < NDP) {
    const v2f wp = *(const v2f*)(W2 + t * 2);
    w2s[t] = h2u((h2){(_Float16)wp.x, (_Float16)wp.y});
  }
  __syncthreads();  // the only barrier

  const int tx = t & 15;
  const int ty = t >> 4;

  float facc[4][4];
#pragma unroll
  for (int ii = 0; ii < 4; ++ii)
#pragma unroll
    for (int jj = 0; jj < 4; ++jj) facc[ii][jj] = 0.f;

  const h2 zero = {(_Float16)0.f, (_Float16)0.f};
#pragma unroll 2
  for (int dpg = 0; dpg < 16; ++dpg) {
    const uint4 w4 = *(const uint4*)(w2s + dpg * 4);  // broadcast
    const h2 wp[4] = {u2h(w4.x), u2h(w4.y), u2h(w4.z), u2h(w4.w)};
#pragma unroll
    for (int q = 0; q < 4; ++q) {
      const int dp = dpg * 4 + q;
      const uint4 hu = *(const uint4*)(his2 + dp * 64 + ty * 4);  // 2-way free
      const uint4 ju = *(const uint4*)(hjs2 + dp * 64 + tx * 4);  // 2-way free
      const h2 hiv[4] = {u2h(hu.x), u2h(hu.y), u2h(hu.z), u2h(hu.w)};
      const h2 hjv[4] = {u2h(ju.x), u2h(ju.y), u2h(ju.z), u2h(ju.w)};
#pragma unroll
      for (int ii = 0; ii < 4; ++ii) {
#pragma unroll
        for (int jj = 0; jj < 4; ++jj) {
          h2 s = hiv[ii] + hjv[jj];                  // v_pk_add_f16
          s = __builtin_elementwise_max(s, zero);    // packed max
          facc[ii][jj] = __builtin_amdgcn_fdot2(s, wp[q], facc[ii][jj], false);
        }
      }
    }
  }

#pragma unroll
  for (int ii = 0; ii < 4; ++ii) {
    float* o = out + (size_t)(ibase + ty * 4 + ii) * NROWS + jbase + tx * 4;
    *(float4*)o = (float4){facc[ii][0] + bias, facc[ii][1] + bias,
                           facc[ii][2] + bias, facc[ii][3] + bias};
  }
}

extern "C" void kernel_launch(void* const* d_in, const int* in_sizes, int n_in,
                              void* d_out, int out_size, void* d_ws, size_t ws_size,
                              hipStream_t stream) {
  const float* z_i = (const float*)d_in[0];
  const float* z_j = (const float*)d_in[1];
  const float* W1  = (const float*)d_in[2];
  const float* b1  = (const float*)d_in[3];
  const float* W2  = (const float*)d_in[4];
  const float* b2  = (const float*)d_in[5];
  float* out = (float*)d_out;

  unsigned* hi2T = (unsigned*)d_ws;             // [64][2048] half2 -> 512 KB
  unsigned* hj2T = hi2T + (size_t)NDP * NROWS;  // [64][2048] half2 -> 512 KB

  prep_kernel<<<dim3(512, 2), 256, 0, stream>>>(z_i, z_j, W1, b1, hi2T, hj2T);
  score_kernel<<<dim3(32, 32), 256, 0, stream>>>(hi2T, hj2T, W2, b2, out);
}